// Round 6
// baseline (9417.890 us; speedup 1.0000x reference)
//
#include <hip/hip_runtime.h>
#include <math.h>

// ---------------------------------------------------------------------------
// Correctness round: fp32 OUTPUTS (reference returns jnp.float32 -> d_out is
// float*; rounds 3-5's bit-identical 0.1733 absmax was bf16-written output
// read back as fp32). Per-array runtime dtype detection (bf16/fp32/zero) for
// inputs, fp64 sub-MLP (+in-block top-8, jax tie rule), fp32 mm/fusion MLPs.
// ---------------------------------------------------------------------------

#define BN 65536

// ws layout (bytes)
#define WS_MASKS 0u             // BN*8 = 512 KB per-row top-8 masks
#define WS_FLAGS (1u << 20)     // 22 ints

enum { R_X = 0, R_Y, R_SW1, R_SB1, R_SW2, R_SB2, R_SWD, R_SBD,
       R_MW1, R_MB1, R_MW2, R_MB2, R_MWD, R_MBD, R_ATTW, R_ATTB,
       R_FW1, R_FB1, R_FW2, R_FB2, R_FWD, R_FBD, N_ROLES };

__device__ __forceinline__ float bf2f(unsigned short u) {
    return __uint_as_float((unsigned)u << 16);
}
// fl: 1=bf16, 0=fp32, 2=zero
__device__ __forceinline__ float loadf(const void* p, size_t i, int fl) {
    return fl == 1 ? bf2f(((const unsigned short*)p)[i])
         : fl == 0 ? ((const float*)p)[i] : 0.f;
}
__device__ __forceinline__ double loadd(const void* p, size_t i, int fl) {
    return fl == 1 ? (double)bf2f(((const unsigned short*)p)[i])
         : fl == 0 ? (double)((const float*)p)[i] : 0.0;
}

// ---------------------------------------------------------------------------
// Detector: one block per array. Sample u16 at 4-byte boundaries (in-bounds
// under either dtype since nsamp <= n/2). bf16 data -> real bf16 exponents,
// mostly in [100,126]; fp32 data -> low mantissa halves, ~10% in band.
// All-zero samples -> ZERO (biases).
// ---------------------------------------------------------------------------
struct DetArgs { const void* p[N_ROLES]; int n[N_ROLES]; };

__global__ __launch_bounds__(256) void detect_kernel(DetArgs da, int* flags) {
    const int role = blockIdx.x;
    const unsigned short* u = (const unsigned short*)da.p[role];
    int nsamp = da.n[role] / 2;
    if (nsamp > 4096) nsamp = 4096;
    __shared__ int band, nz;
    if (threadIdx.x == 0) { band = 0; nz = 0; }
    __syncthreads();
    int lb = 0, lnz = 0;
    for (int i = threadIdx.x; i < nsamp; i += 256) {
        const unsigned short v = u[2 * i];
        if (v) {
            ++lnz;
            const int e = (v >> 7) & 0xFF;
            if (e >= 100 && e <= 126) ++lb;
        }
    }
    atomicAdd(&band, lb);
    atomicAdd(&nz, lnz);
    __syncthreads();
    if (threadIdx.x == 0)
        flags[role] = (nz == 0) ? 2 : ((band * 2 > nz) ? 1 : 0);
}

// ---------------------------------------------------------------------------
// K1: fp64 sub-MLP, 8 rows/block, 256 threads. Writes fp32 out_sub to d_out
// and the per-row top-8 mask to ws.
// ---------------------------------------------------------------------------
__global__ __launch_bounds__(256)
void sub_kernel(const void* __restrict__ x,
                const void* __restrict__ W1, const void* __restrict__ b1,
                const void* __restrict__ W2, const void* __restrict__ b2,
                const void* __restrict__ Wd, const void* __restrict__ bd,
                const int* __restrict__ flags,
                float* __restrict__ outf,
                unsigned long long* __restrict__ masks)
{
    __shared__ double xs[8 * 128];
    __shared__ double h[8 * 512];
    __shared__ double ob[8 * 64];
    const int fx = flags[R_X], f1 = flags[R_SW1], fb1 = flags[R_SB1],
              f2 = flags[R_SW2], fb2 = flags[R_SB2],
              f3 = flags[R_SWD], fb3 = flags[R_SBD];
    const int t = threadIdx.x;
    const int r0 = blockIdx.x * 8;

    for (int i = t; i < 8 * 128; i += 256)
        xs[i] = loadd(x, (size_t)(r0 + (i >> 7)) * 128 + (i & 127), fx);
    __syncthreads();

    // ---- layer 1: K=128, cols c0=t, c1=t+256 ----
    {
        const int c0 = t, c1 = t + 256;
        double a0[8], a1[8];
#pragma unroll
        for (int r = 0; r < 8; ++r) { a0[r] = 0.0; a1[r] = 0.0; }
        for (int k = 0; k < 128; ++k) {
            const double w0 = loadd(W1, (size_t)k * 512 + c0, f1);
            const double w1 = loadd(W1, (size_t)k * 512 + c1, f1);
#pragma unroll
            for (int r = 0; r < 8; ++r) {
                const double xv = xs[r * 128 + k];
                a0[r] = fma(xv, w0, a0[r]);
                a1[r] = fma(xv, w1, a1[r]);
            }
        }
        const double bb0 = loadd(b1, c0, fb1), bb1 = loadd(b1, c1, fb1);
#pragma unroll
        for (int r = 0; r < 8; ++r) {
            const double v0 = a0[r] + bb0, v1 = a1[r] + bb1;
            h[r * 512 + c0] = v0 > 0.0 ? v0 : 0.0;
            h[r * 512 + c1] = v1 > 0.0 ? v1 : 0.0;
        }
    }
    __syncthreads();

    // ---- layer 2: K=512, in-place ----
    {
        const int c0 = t, c1 = t + 256;
        double a0[8], a1[8];
#pragma unroll
        for (int r = 0; r < 8; ++r) { a0[r] = 0.0; a1[r] = 0.0; }
        for (int k = 0; k < 512; ++k) {
            const double w0 = loadd(W2, (size_t)k * 512 + c0, f2);
            const double w1 = loadd(W2, (size_t)k * 512 + c1, f2);
#pragma unroll
            for (int r = 0; r < 8; ++r) {
                const double hv = h[r * 512 + k];
                a0[r] = fma(hv, w0, a0[r]);
                a1[r] = fma(hv, w1, a1[r]);
            }
        }
        __syncthreads();  // all reads of h done
        const double bb0 = loadd(b2, c0, fb2), bb1 = loadd(b2, c1, fb2);
#pragma unroll
        for (int r = 0; r < 8; ++r) {
            const double v0 = a0[r] + bb0, v1 = a1[r] + bb1;
            h[r * 512 + c0] = v0 > 0.0 ? v0 : 0.0;
            h[r * 512 + c1] = v1 > 0.0 ? v1 : 0.0;
        }
    }
    __syncthreads();

    // ---- layer 3: K=512, N=64; thread t: col t&63, rows 2*(t>>6), +1 ----
    {
        const int c = t & 63, rp = t >> 6;
        double a3[2] = {0.0, 0.0};
        for (int k = 0; k < 512; ++k) {
            const double wv = loadd(Wd, (size_t)k * 64 + c, f3);
            a3[0] = fma(h[(2 * rp) * 512 + k], wv, a3[0]);
            a3[1] = fma(h[(2 * rp + 1) * 512 + k], wv, a3[1]);
        }
        const double bb = loadd(bd, c, fb3);
#pragma unroll
        for (int i = 0; i < 2; ++i) {
            const int r = 2 * rp + i;
            const double v = a3[i] + bb;  // output layer: no relu
            ob[r * 64 + c] = v;
            outf[(size_t)(r0 + r) * 64 + c] = (float)v;
        }
    }
    __syncthreads();

    // ---- in-block top-8 per row (strict '>' insertion: jax tie rule) ----
    if (t < 8) {
        const double* rowp = &ob[t * 64];
        double vals[8];
        int idxs[8];
#pragma unroll
        for (int j = 0; j < 8; ++j) { vals[j] = -1.0e300; idxs[j] = 0; }
        for (int i = 0; i < 64; ++i) {
            const double v = rowp[i];
            if (v > vals[7]) {
                int p = 7;
                while (p > 0 && v > vals[p - 1]) {
                    vals[p] = vals[p - 1];
                    idxs[p] = idxs[p - 1];
                    --p;
                }
                vals[p] = v;
                idxs[p] = i;
            }
        }
        unsigned long long m = 0ull;
#pragma unroll
        for (int j = 0; j < 8; ++j) m |= (1ull << idxs[j]);
        masks[r0 + t] = m;
    }
}

// ---------------------------------------------------------------------------
// Shared fp32 scalar 128->512->512->64 MLP for 16 rows, 256 threads.
// Writes fp32 to out.
// ---------------------------------------------------------------------------
__device__ void mlp128_f32(const float* __restrict__ xs, float* __restrict__ h,
                           const void* __restrict__ W1, const void* __restrict__ b1,
                           const void* __restrict__ W2, const void* __restrict__ b2,
                           const void* __restrict__ Wd, const void* __restrict__ bd,
                           int f1, int fb1, int f2, int fb2, int f3, int fb3,
                           int r0, float* __restrict__ out)
{
    const int t = threadIdx.x;
    const int c0 = t, c1 = t + 256;

    float a0[16], a1[16];
#pragma unroll
    for (int r = 0; r < 16; ++r) { a0[r] = 0.f; a1[r] = 0.f; }
    for (int k = 0; k < 128; ++k) {
        const float w0 = loadf(W1, (size_t)k * 512 + c0, f1);
        const float w1 = loadf(W1, (size_t)k * 512 + c1, f1);
#pragma unroll
        for (int r = 0; r < 16; ++r) {
            const float xv = xs[r * 128 + k];
            a0[r] = fmaf(xv, w0, a0[r]);
            a1[r] = fmaf(xv, w1, a1[r]);
        }
    }
    {
        const float bb0 = loadf(b1, c0, fb1), bb1 = loadf(b1, c1, fb1);
#pragma unroll
        for (int r = 0; r < 16; ++r) {
            const float v0 = a0[r] + bb0, v1 = a1[r] + bb1;
            h[r * 512 + c0] = v0 > 0.f ? v0 : 0.f;
            h[r * 512 + c1] = v1 > 0.f ? v1 : 0.f;
        }
    }
    __syncthreads();

#pragma unroll
    for (int r = 0; r < 16; ++r) { a0[r] = 0.f; a1[r] = 0.f; }
    for (int k = 0; k < 512; ++k) {
        const float w0 = loadf(W2, (size_t)k * 512 + c0, f2);
        const float w1 = loadf(W2, (size_t)k * 512 + c1, f2);
#pragma unroll
        for (int r = 0; r < 16; ++r) {
            const float hv = h[r * 512 + k];
            a0[r] = fmaf(hv, w0, a0[r]);
            a1[r] = fmaf(hv, w1, a1[r]);
        }
    }
    __syncthreads();
    {
        const float bb0 = loadf(b2, c0, fb2), bb1 = loadf(b2, c1, fb2);
#pragma unroll
        for (int r = 0; r < 16; ++r) {
            const float v0 = a0[r] + bb0, v1 = a1[r] + bb1;
            h[r * 512 + c0] = v0 > 0.f ? v0 : 0.f;
            h[r * 512 + c1] = v1 > 0.f ? v1 : 0.f;
        }
    }
    __syncthreads();

    const int c = t & 63, rb = (t >> 6) * 4;
    float a3[4] = {0.f, 0.f, 0.f, 0.f};
    for (int k = 0; k < 512; ++k) {
        const float wv = loadf(Wd, (size_t)k * 64 + c, f3);
#pragma unroll
        for (int i = 0; i < 4; ++i) a3[i] = fmaf(h[(rb + i) * 512 + k], wv, a3[i]);
    }
    {
        const float bb = loadf(bd, c, fb3);
#pragma unroll
        for (int i = 0; i < 4; ++i)
            out[(size_t)(r0 + rb + i) * 64 + c] = a3[i] + bb;
    }
}

// ---------------------------------------------------------------------------
// K2: mm MLP from masked y (masks from ws). fp32 out to d_out[BN*64..].
// ---------------------------------------------------------------------------
__global__ __launch_bounds__(256)
void mm_kernel(const unsigned long long* __restrict__ masks,
               const void* __restrict__ y,
               const void* __restrict__ W1, const void* __restrict__ b1,
               const void* __restrict__ W2, const void* __restrict__ b2,
               const void* __restrict__ Wd, const void* __restrict__ bd,
               const int* __restrict__ flags, float* __restrict__ out)
{
    __shared__ float xs[16 * 128];
    __shared__ float h[16 * 512];
    const int fy = flags[R_Y];
    const int r0 = blockIdx.x * 16;
    for (int i = threadIdx.x; i < 16 * 128; i += 256) {
        const int r = i >> 7, k = i & 127;
        const bool keep = (masks[r0 + r] >> (k >> 1)) & 1ull;
        xs[i] = keep ? loadf(y, (size_t)(r0 + r) * 128 + k, fy) : 0.f;
    }
    __syncthreads();
    mlp128_f32(xs, h, W1, b1, W2, b2, Wd, bd,
               flags[R_MW1], flags[R_MB1], flags[R_MW2], flags[R_MB2],
               flags[R_MWD], flags[R_MBD], r0, out);
}

// ---------------------------------------------------------------------------
// K3: cat = [out_sub, out_mm] (fp32 from d_out) -> sigmoid attention gate ->
// fusion MLP. fp32 out to d_out[2*BN*64..].
// ---------------------------------------------------------------------------
__global__ __launch_bounds__(256)
void fusion_kernel(const float* __restrict__ subf, const float* __restrict__ mmf,
                   const void* __restrict__ attw, const void* __restrict__ attb,
                   const void* __restrict__ W1, const void* __restrict__ b1,
                   const void* __restrict__ W2, const void* __restrict__ b2,
                   const void* __restrict__ Wd, const void* __restrict__ bd,
                   const int* __restrict__ flags, float* __restrict__ out)
{
    __shared__ float xs[16 * 128];
    __shared__ float h[16 * 512];
    const int fw = flags[R_ATTW], fb = flags[R_ATTB];
    const int r0 = blockIdx.x * 16;
    const int t = threadIdx.x;

    for (int i = t; i < 16 * 128; i += 256) {
        const int r = i >> 7, cc = i & 127;
        const size_t row = (size_t)(r0 + r);
        xs[i] = (cc < 64) ? subf[row * 64 + cc] : mmf[row * 64 + (cc - 64)];
    }
    __syncthreads();

    const int c = t & 127, rh = t >> 7;
    float acc[8];
#pragma unroll
    for (int j = 0; j < 8; ++j) acc[j] = 0.f;
    for (int k = 0; k < 128; ++k) {
        const float wv = loadf(attw, (size_t)k * 128 + c, fw);
#pragma unroll
        for (int j = 0; j < 8; ++j)
            acc[j] = fmaf(xs[(2 * j + rh) * 128 + k], wv, acc[j]);
    }
    const float ab = loadf(attb, c, fb);
    float gated[8];
#pragma unroll
    for (int j = 0; j < 8; ++j) {
        const int r = 2 * j + rh;
        const float pre = acc[j] + ab;
        const float s = 1.f / (1.f + expf(-pre));
        gated[j] = xs[r * 128 + c] * s;
    }
    __syncthreads();
#pragma unroll
    for (int j = 0; j < 8; ++j) xs[(2 * j + rh) * 128 + c] = gated[j];
    __syncthreads();

    mlp128_f32(xs, h, W1, b1, W2, b2, Wd, bd,
               flags[R_FW1], flags[R_FB1], flags[R_FW2], flags[R_FB2],
               flags[R_FWD], flags[R_FBD], r0, out);
}

// ---------------------------------------------------------------------------
extern "C" void kernel_launch(void* const* d_in, const int* in_sizes, int n_in,
                              void* d_out, int out_size, void* d_ws, size_t ws_size,
                              hipStream_t stream)
{
    // ---- resolve input order by size signature (dict order vs sorted) ----
    static const int dictSizes[23] = {8388608, 8388608, 65536, 512, 262144, 512,
                                      32768, 64, 65536, 512, 262144, 512, 32768, 64,
                                      16384, 128, 65536, 512, 262144, 512, 32768, 64, 1};
    static const int dictRole[23]  = {R_X, R_Y, R_SW1, R_SB1, R_SW2, R_SB2, R_SWD, R_SBD,
                                      R_MW1, R_MB1, R_MW2, R_MB2, R_MWD, R_MBD,
                                      R_ATTW, R_ATTB, R_FW1, R_FB1, R_FW2, R_FB2,
                                      R_FWD, R_FBD, -1};
    static const int sortSizes[23] = {128, 16384, 512, 512, 64, 65536, 262144, 32768,
                                      512, 512, 64, 65536, 262144, 32768,
                                      512, 512, 64, 65536, 262144, 32768, 1,
                                      8388608, 8388608};
    static const int sortRole[23]  = {R_ATTB, R_ATTW, R_FB1, R_FB2, R_FBD, R_FW1,
                                      R_FW2, R_FWD, R_MB1, R_MB2, R_MBD, R_MW1,
                                      R_MW2, R_MWD, R_SB1, R_SB2, R_SBD, R_SW1,
                                      R_SW2, R_SWD, -1, R_X, R_Y};
    const void* rp[N_ROLES];
    int rs[N_ROLES];
    for (int i = 0; i < 23 && i < n_in; ++i)
        if (dictRole[i] >= 0) { rp[dictRole[i]] = d_in[i]; rs[dictRole[i]] = in_sizes[i]; }
    {
        bool dictOk = (n_in >= 22);
        for (int i = 0; i < 22 && dictOk; ++i)
            if (in_sizes[i] != dictSizes[i]) dictOk = false;
        if (!dictOk) {
            bool sortOk = (n_in >= 23);
            for (int i = 0; i < 23 && sortOk; ++i)
                if (in_sizes[i] != sortSizes[i]) sortOk = false;
            if (sortOk)
                for (int i = 0; i < 23; ++i)
                    if (sortRole[i] >= 0) { rp[sortRole[i]] = d_in[i]; rs[sortRole[i]] = in_sizes[i]; }
        }
    }

    unsigned long long* masks = (unsigned long long*)((char*)d_ws + WS_MASKS);
    int* flags = (int*)((char*)d_ws + WS_FLAGS);

    float* out_f  = (float*)d_out;
    float* sub_o  = out_f;
    float* mm_o   = out_f + (size_t)BN * 64;
    float* fus_o  = out_f + (size_t)2 * BN * 64;

    DetArgs da;
    for (int r = 0; r < N_ROLES; ++r) { da.p[r] = rp[r]; da.n[r] = rs[r]; }
    detect_kernel<<<N_ROLES, 256, 0, stream>>>(da, flags);

    sub_kernel<<<BN / 8, 256, 0, stream>>>(
        rp[R_X], rp[R_SW1], rp[R_SB1], rp[R_SW2], rp[R_SB2], rp[R_SWD], rp[R_SBD],
        flags, sub_o, masks);

    mm_kernel<<<BN / 16, 256, 0, stream>>>(
        masks, rp[R_Y], rp[R_MW1], rp[R_MB1], rp[R_MW2], rp[R_MB2],
        rp[R_MWD], rp[R_MBD], flags, mm_o);

    fusion_kernel<<<BN / 16, 256, 0, stream>>>(
        sub_o, mm_o, rp[R_ATTW], rp[R_ATTB], rp[R_FW1], rp[R_FB1],
        rp[R_FW2], rp[R_FB2], rp[R_FWD], rp[R_FBD], flags, fus_o);
}

// Round 7
// 2988.612 us; speedup vs baseline: 3.1513x; 3.1513x over previous
//
#include <hip/hip_runtime.h>
#include <math.h>

// ---------------------------------------------------------------------------
// MFMA round. fp32 outputs (validated r6). Per-array dtype detection
// (bf16/fp32/zero). All three MLPs: split-bf16 MFMA (hi/lo planes, 3 terms,
// ~1e-6 abs accuracy). Top-8 correctness vs fp64 reference guaranteed by a
// margin-gated fp64 rescue pass (rows with 8th/9th gap < 1e-4 recomputed).
// ---------------------------------------------------------------------------

typedef __bf16 bf16x8  __attribute__((ext_vector_type(8)));
typedef float  floatx4 __attribute__((ext_vector_type(4)));
#define MFMA(a,b,c) __builtin_amdgcn_mfma_f32_16x16x32_bf16((a),(b),(c),0,0,0)

#define BN 65536
#define IST 136     // input-plane LDS stride (128 + 8)
#define HSTR 520    // hidden-plane LDS stride (512 + 8) -> 2-way bank alias only
#define MARGIN 1e-4f

// packed plane sizes/offsets (bf16 elements); hi at OFF, lo at OFF+SZ
#define SZ_W1 65536
#define SZ_W2 262144
#define SZ_WD 32768
#define SZ_ATT 16384
#define OFF_SW1 0
#define OFF_SW2 (OFF_SW1 + 2*SZ_W1)
#define OFF_SWD (OFF_SW2 + 2*SZ_W2)
#define OFF_MW1 (OFF_SWD + 2*SZ_WD)
#define OFF_MW2 (OFF_MW1 + 2*SZ_W1)
#define OFF_MWD (OFF_MW2 + 2*SZ_W2)
#define OFF_FW1 (OFF_MWD + 2*SZ_WD)
#define OFF_FW2 (OFF_FW1 + 2*SZ_W1)
#define OFF_FWD (OFF_FW2 + 2*SZ_W2)
#define OFF_ATT (OFF_FWD + 2*SZ_WD)

// ws byte offsets (pack ends at ~4.4 MB)
#define WS_MASKS (5u << 20)     // BN * 8 B
#define WS_RROWS (6u << 20)     // up to BN ints
#define WS_RCNT  (7u << 20)     // 1 int
#define WS_FLAGS ((7u << 20) + 256)

enum { R_X = 0, R_Y, R_SW1, R_SB1, R_SW2, R_SB2, R_SWD, R_SBD,
       R_MW1, R_MB1, R_MW2, R_MB2, R_MWD, R_MBD, R_ATTW, R_ATTB,
       R_FW1, R_FB1, R_FW2, R_FB2, R_FWD, R_FBD, N_ROLES };

__device__ __forceinline__ float bf2f(unsigned short u) {
    return __uint_as_float((unsigned)u << 16);
}
// fl: 1=bf16, 0=fp32, 2=zero
__device__ __forceinline__ float loadf(const void* p, size_t i, int fl) {
    return fl == 1 ? bf2f(((const unsigned short*)p)[i])
         : fl == 0 ? ((const float*)p)[i] : 0.f;
}
__device__ __forceinline__ double loadd(const void* p, size_t i, int fl) {
    return fl == 1 ? (double)bf2f(((const unsigned short*)p)[i])
         : fl == 0 ? (double)((const float*)p)[i] : 0.0;
}
struct bf2 { __bf16 hi, lo; };
__device__ __forceinline__ bf2 split2(float v) {
    bf2 r;
    r.hi = (__bf16)v;
    r.lo = (__bf16)(v - (float)r.hi);
    return r;
}

// ---------------------------------------------------------------------------
// detect: per-array dtype (1=bf16, 0=fp32, 2=zero). Also zeroes rescue count.
// ---------------------------------------------------------------------------
struct DetArgs { const void* p[N_ROLES]; int n[N_ROLES]; };

__global__ __launch_bounds__(256) void detect_kernel(DetArgs da, int* flags, int* rcnt) {
    const int role = blockIdx.x;
    if (role == 0 && threadIdx.x == 0) *rcnt = 0;
    const unsigned short* u = (const unsigned short*)da.p[role];
    int nsamp = da.n[role] / 2;
    if (nsamp > 4096) nsamp = 4096;
    __shared__ int band, nz;
    if (threadIdx.x == 0) { band = 0; nz = 0; }
    __syncthreads();
    int lb = 0, lnz = 0;
    for (int i = threadIdx.x; i < nsamp; i += 256) {
        const unsigned short v = u[2 * i];
        if (v) {
            ++lnz;
            const int e = (v >> 7) & 0xFF;
            if (e >= 100 && e <= 126) ++lb;
        }
    }
    atomicAdd(&band, lb);
    atomicAdd(&nz, lnz);
    __syncthreads();
    if (threadIdx.x == 0)
        flags[role] = (nz == 0) ? 2 : ((band * 2 > nz) ? 1 : 0);
}

// ---------------------------------------------------------------------------
// pack: [K x N] -> MFMA B-frag hi/lo planes. Frag for tile (kt,nt): lane l,
// j=0..7 holds W[kt*32 + (l>>4)*8 + j][nt*16 + (l&15)].
// ---------------------------------------------------------------------------
struct PackArgs { const void* src[10]; int K[10], N[10], off[10], role[10]; };

__global__ __launch_bounds__(256) void pack_weights(PackArgs pa, __bf16* dst,
                                                    const int* __restrict__ flags) {
    const int m = blockIdx.y;
    const int fl = flags[pa.role[m]];
    const int K = pa.K[m], N = pa.N[m];
    const int KT = K >> 5, NT = N >> 4;
    const int total = KT * NT * 64;
    const int t = blockIdx.x * 256 + threadIdx.x;
    if (t >= total) return;
    const int l = t & 63;
    const int idx = t >> 6;            // nt*KT + kt
    const int kt = idx % KT;
    const int nt = idx / KT;
    const int k0 = kt * 32 + ((l >> 4) << 3);
    const int n  = nt * 16 + (l & 15);
    __bf16* dh = dst + pa.off[m] + (size_t)t * 8;
    __bf16* dl = dh + K * N;
#pragma unroll
    for (int j = 0; j < 8; ++j) {
        const bf2 s = split2(loadf(pa.src[m], (size_t)(k0 + j) * N + n, fl));
        dh[j] = s.hi;
        dl[j] = s.lo;
    }
}

// ---------------------------------------------------------------------------
// Core 3-layer MFMA MLP (16 rows, 512 threads = 8 waves). Input from ixs
// hi/lo planes; h planes in LDS (in-place L2); fp32 out. SUB also mirrors
// layer-3 output into outb (LDS) for top-k.
// ---------------------------------------------------------------------------
template <bool SUB>
__device__ __forceinline__ void mlp_core(
    const __bf16* __restrict__ ix0, const __bf16* __restrict__ ix1,
    __bf16* __restrict__ h0, __bf16* __restrict__ h1,
    const __bf16* __restrict__ p1h, const __bf16* __restrict__ p1l,
    const __bf16* __restrict__ p2h, const __bf16* __restrict__ p2l,
    const __bf16* __restrict__ pdh, const __bf16* __restrict__ pdl,
    const void* __restrict__ b1, int fb1,
    const void* __restrict__ b2, int fb2,
    const void* __restrict__ bd, int fbd,
    int r0, float* __restrict__ out, float* __restrict__ outb)
{
    const int tid = threadIdx.x;
    const int l = tid & 63, w = tid >> 6, l15 = l & 15, q = l >> 4;

    // ---- layer 1: K=128, wave w owns 64-col slab ----
    floatx4 acc[4];
#pragma unroll
    for (int nt = 0; nt < 4; ++nt) acc[nt] = (floatx4)0.0f;
#pragma unroll
    for (int kt = 0; kt < 4; ++kt) {
        const int ab = l15 * IST + kt * 32 + q * 8;
        const bf16x8 ahi = *(const bf16x8*)&ix0[ab];
        const bf16x8 alo = *(const bf16x8*)&ix1[ab];
#pragma unroll
        for (int nt = 0; nt < 4; ++nt) {
            const size_t fi = ((((size_t)(w * 4 + nt)) * 4 + kt) * 64 + l) * 8;
            const bf16x8 bhi = *(const bf16x8*)(p1h + fi);
            const bf16x8 blo = *(const bf16x8*)(p1l + fi);
            acc[nt] = MFMA(alo, bhi, acc[nt]);
            acc[nt] = MFMA(ahi, blo, acc[nt]);
            acc[nt] = MFMA(ahi, bhi, acc[nt]);
        }
    }
#pragma unroll
    for (int nt = 0; nt < 4; ++nt) {
        const int col = w * 64 + nt * 16 + l15;
        const float bias = loadf(b1, col, fb1);
#pragma unroll
        for (int r = 0; r < 4; ++r) {
            const int rowl = q * 4 + r;
            float v = acc[nt][r] + bias;
            v = v > 0.f ? v : 0.f;
            const bf2 s = split2(v);
            h0[rowl * HSTR + col] = s.hi;
            h1[rowl * HSTR + col] = s.lo;
        }
    }
    __syncthreads();

    // ---- layer 2: K=512, in-place ----
    floatx4 acc2[4];
#pragma unroll
    for (int nt = 0; nt < 4; ++nt) acc2[nt] = (floatx4)0.0f;
    for (int kt = 0; kt < 16; ++kt) {
        const int ab = l15 * HSTR + kt * 32 + q * 8;
        const bf16x8 ahi = *(const bf16x8*)&h0[ab];
        const bf16x8 alo = *(const bf16x8*)&h1[ab];
#pragma unroll
        for (int nt = 0; nt < 4; ++nt) {
            const size_t fi = ((((size_t)(w * 4 + nt)) * 16 + kt) * 64 + l) * 8;
            const bf16x8 bhi = *(const bf16x8*)(p2h + fi);
            const bf16x8 blo = *(const bf16x8*)(p2l + fi);
            acc2[nt] = MFMA(alo, bhi, acc2[nt]);
            acc2[nt] = MFMA(ahi, blo, acc2[nt]);
            acc2[nt] = MFMA(ahi, bhi, acc2[nt]);
        }
    }
    __syncthreads();  // all reads of h done before overwrite
#pragma unroll
    for (int nt = 0; nt < 4; ++nt) {
        const int col = w * 64 + nt * 16 + l15;
        const float bias = loadf(b2, col, fb2);
#pragma unroll
        for (int r = 0; r < 4; ++r) {
            const int rowl = q * 4 + r;
            float v = acc2[nt][r] + bias;
            v = v > 0.f ? v : 0.f;
            const bf2 s = split2(v);
            h0[rowl * HSTR + col] = s.hi;
            h1[rowl * HSTR + col] = s.lo;
        }
    }
    __syncthreads();

    // ---- layer 3: K=512, N=64; waves 0..3 (nt=w) ----
    if (w < 4) {
        floatx4 a3 = (floatx4)0.0f;
        for (int kt = 0; kt < 16; ++kt) {
            const int ab = l15 * HSTR + kt * 32 + q * 8;
            const bf16x8 ahi = *(const bf16x8*)&h0[ab];
            const bf16x8 alo = *(const bf16x8*)&h1[ab];
            const size_t fi = (((size_t)(w * 16 + kt)) * 64 + l) * 8;
            const bf16x8 bhi = *(const bf16x8*)(pdh + fi);
            const bf16x8 blo = *(const bf16x8*)(pdl + fi);
            a3 = MFMA(alo, bhi, a3);
            a3 = MFMA(ahi, blo, a3);
            a3 = MFMA(ahi, bhi, a3);
        }
        const int col = w * 16 + l15;
        const float bias = loadf(bd, col, fbd);
#pragma unroll
        for (int r = 0; r < 4; ++r) {
            const int rowl = q * 4 + r;
            const float v = a3[r] + bias;  // no relu on output layer
            out[(size_t)(r0 + rowl) * 64 + col] = v;
            if (SUB) outb[rowl * 64 + col] = v;
        }
    }
    if (SUB) __syncthreads();
}

// ---------------------------------------------------------------------------
// K1: sub MLP + per-row top-8 mask + margin-gated rescue list.
// ---------------------------------------------------------------------------
__global__ __launch_bounds__(512, 4)
void sub_mfma(const void* __restrict__ x, const __bf16* __restrict__ wpack,
              const void* __restrict__ b1, const void* __restrict__ b2,
              const void* __restrict__ bd, const int* __restrict__ flags,
              float* __restrict__ out, unsigned long long* __restrict__ masks,
              int* __restrict__ rrows, int* __restrict__ rcnt)
{
    __shared__ __align__(16) __bf16 ixs[2][16 * IST];
    __shared__ __align__(16) __bf16 h[2][16 * HSTR];
    __shared__ float outb[16 * 64];
    const int fx = flags[R_X];
    const int r0 = blockIdx.x * 16;

    for (int i = threadIdx.x; i < 2048; i += 512) {
        const int r = i >> 7, c = i & 127;
        const bf2 s = split2(loadf(x, (size_t)(r0 + r) * 128 + c, fx));
        ixs[0][r * IST + c] = s.hi;
        ixs[1][r * IST + c] = s.lo;
    }
    __syncthreads();

    mlp_core<true>(ixs[0], ixs[1], h[0], h[1],
                   wpack + OFF_SW1, wpack + OFF_SW1 + SZ_W1,
                   wpack + OFF_SW2, wpack + OFF_SW2 + SZ_W2,
                   wpack + OFF_SWD, wpack + OFF_SWD + SZ_WD,
                   b1, flags[R_SB1], b2, flags[R_SB2], bd, flags[R_SBD],
                   r0, out, outb);

    // top-9 per row (strict '>' insertion: jax tie rule -> lowest index wins)
    if (threadIdx.x < 16) {
        const float* rowp = &outb[threadIdx.x * 64];
        float vals[9];
        int idxs[9];
#pragma unroll
        for (int j = 0; j < 9; ++j) { vals[j] = -__builtin_inff(); idxs[j] = 0; }
        for (int i = 0; i < 64; ++i) {
            const float v = rowp[i];
            if (v > vals[8]) {
                int p = 8;
                while (p > 0 && v > vals[p - 1]) {
                    vals[p] = vals[p - 1];
                    idxs[p] = idxs[p - 1];
                    --p;
                }
                vals[p] = v;
                idxs[p] = i;
            }
        }
        unsigned long long m = 0ull;
#pragma unroll
        for (int j = 0; j < 8; ++j) m |= (1ull << idxs[j]);
        masks[r0 + threadIdx.x] = m;
        if (vals[7] - vals[8] < MARGIN) {
            const int slot = atomicAdd(rcnt, 1);
            rrows[slot] = r0 + threadIdx.x;
        }
    }
}

// ---------------------------------------------------------------------------
// K1b: fp64 rescue for marginal rows — recompute sub row exactly, fix mask
// and out_sub row.
// ---------------------------------------------------------------------------
__global__ __launch_bounds__(256)
void rescue_kernel(const void* __restrict__ x,
                   const void* __restrict__ W1, const void* __restrict__ b1,
                   const void* __restrict__ W2, const void* __restrict__ b2,
                   const void* __restrict__ Wd, const void* __restrict__ bd,
                   const int* __restrict__ flags,
                   const int* __restrict__ rrows, const int* __restrict__ rcnt,
                   float* __restrict__ out, unsigned long long* __restrict__ masks)
{
    __shared__ double xs[128];
    __shared__ double h[512];
    __shared__ double ob[64];
    const int fx = flags[R_X], f1 = flags[R_SW1], fb1 = flags[R_SB1],
              f2 = flags[R_SW2], fb2 = flags[R_SB2],
              f3 = flags[R_SWD], fb3 = flags[R_SBD];
    const int t = threadIdx.x;
    const int n = *rcnt;

    for (int ii = blockIdx.x; ii < n; ii += gridDim.x) {
        const int row = rrows[ii];
        for (int i = t; i < 128; i += 256) xs[i] = loadd(x, (size_t)row * 128 + i, fx);
        __syncthreads();
        // L1
        {
            const int c0 = t, c1 = t + 256;
            double a0 = 0.0, a1 = 0.0;
            for (int k = 0; k < 128; ++k) {
                a0 = fma(xs[k], loadd(W1, (size_t)k * 512 + c0, f1), a0);
                a1 = fma(xs[k], loadd(W1, (size_t)k * 512 + c1, f1), a1);
            }
            const double v0 = a0 + loadd(b1, c0, fb1), v1 = a1 + loadd(b1, c1, fb1);
            __syncthreads();
            h[c0] = v0 > 0.0 ? v0 : 0.0;
            h[c1] = v1 > 0.0 ? v1 : 0.0;
        }
        __syncthreads();
        // L2 (in-place)
        {
            const int c0 = t, c1 = t + 256;
            double a0 = 0.0, a1 = 0.0;
            for (int k = 0; k < 512; ++k) {
                a0 = fma(h[k], loadd(W2, (size_t)k * 512 + c0, f2), a0);
                a1 = fma(h[k], loadd(W2, (size_t)k * 512 + c1, f2), a1);
            }
            __syncthreads();
            const double v0 = a0 + loadd(b2, c0, fb2), v1 = a1 + loadd(b2, c1, fb2);
            h[c0] = v0 > 0.0 ? v0 : 0.0;
            h[c1] = v1 > 0.0 ? v1 : 0.0;
        }
        __syncthreads();
        // L3
        if (t < 64) {
            double a = 0.0;
            for (int k = 0; k < 512; ++k)
                a = fma(h[k], loadd(Wd, (size_t)k * 64 + t, f3), a);
            const double v = a + loadd(bd, t, fb3);
            ob[t] = v;
            out[(size_t)row * 64 + t] = (float)v;
        }
        __syncthreads();
        if (t == 0) {
            double vals[8];
            int idxs[8];
#pragma unroll
            for (int j = 0; j < 8; ++j) { vals[j] = -1.0e300; idxs[j] = 0; }
            for (int i = 0; i < 64; ++i) {
                const double v = ob[i];
                if (v > vals[7]) {
                    int p = 7;
                    while (p > 0 && v > vals[p - 1]) {
                        vals[p] = vals[p - 1];
                        idxs[p] = idxs[p - 1];
                        --p;
                    }
                    vals[p] = v;
                    idxs[p] = i;
                }
            }
            unsigned long long m = 0ull;
#pragma unroll
            for (int j = 0; j < 8; ++j) m |= (1ull << idxs[j]);
            masks[row] = m;
        }
        __syncthreads();
    }
}

// ---------------------------------------------------------------------------
// K2: mm MLP from masked y.
// ---------------------------------------------------------------------------
__global__ __launch_bounds__(512, 4)
void mm_mfma(const unsigned long long* __restrict__ masks,
             const void* __restrict__ y, const __bf16* __restrict__ wpack,
             const void* __restrict__ b1, const void* __restrict__ b2,
             const void* __restrict__ bd, const int* __restrict__ flags,
             float* __restrict__ out)
{
    __shared__ __align__(16) __bf16 ixs[2][16 * IST];
    __shared__ __align__(16) __bf16 h[2][16 * HSTR];
    const int fy = flags[R_Y];
    const int r0 = blockIdx.x * 16;

    for (int i = threadIdx.x; i < 2048; i += 512) {
        const int r = i >> 7, c = i & 127;
        const bool keep = (masks[r0 + r] >> (c >> 1)) & 1ull;
        const float v = keep ? loadf(y, (size_t)(r0 + r) * 128 + c, fy) : 0.f;
        const bf2 s = split2(v);
        ixs[0][r * IST + c] = s.hi;
        ixs[1][r * IST + c] = s.lo;
    }
    __syncthreads();

    mlp_core<false>(ixs[0], ixs[1], h[0], h[1],
                    wpack + OFF_MW1, wpack + OFF_MW1 + SZ_W1,
                    wpack + OFF_MW2, wpack + OFF_MW2 + SZ_W2,
                    wpack + OFF_MWD, wpack + OFF_MWD + SZ_WD,
                    b1, flags[R_MB1], b2, flags[R_MB2], bd, flags[R_MBD],
                    r0, out, nullptr);
}

// ---------------------------------------------------------------------------
// K3: cat (fp32 from d_out) -> sigmoid attention gate -> fusion MLP.
// ---------------------------------------------------------------------------
__global__ __launch_bounds__(512, 4)
void fusion_mfma(const float* __restrict__ subf, const float* __restrict__ mmf,
                 const __bf16* __restrict__ wpack,
                 const void* __restrict__ attb,
                 const void* __restrict__ b1, const void* __restrict__ b2,
                 const void* __restrict__ bd, const int* __restrict__ flags,
                 float* __restrict__ out)
{
    __shared__ __align__(16) __bf16 ixs[2][16 * IST];
    __shared__ __align__(16) __bf16 h[2][16 * HSTR];
    const int tid = threadIdx.x;
    const int l = tid & 63, w = tid >> 6, l15 = l & 15, q = l >> 4;
    const int r0 = blockIdx.x * 16;

    for (int i = tid; i < 2048; i += 512) {
        const int r = i >> 7, c = i & 127;
        const size_t row = (size_t)(r0 + r);
        const float v = (c < 64) ? subf[row * 64 + c] : mmf[row * 64 + (c - 64)];
        const bf2 s = split2(v);
        ixs[0][r * IST + c] = s.hi;
        ixs[1][r * IST + c] = s.lo;
    }
    __syncthreads();

    // attention: N=128, wave w owns 16-col tile nt=w
    floatx4 aacc = (floatx4)0.0f;
    const __bf16* path = wpack + OFF_ATT;
    const __bf16* patl = path + SZ_ATT;
#pragma unroll
    for (int kt = 0; kt < 4; ++kt) {
        const int ab = l15 * IST + kt * 32 + q * 8;
        const bf16x8 ahi = *(const bf16x8*)&ixs[0][ab];
        const bf16x8 alo = *(const bf16x8*)&ixs[1][ab];
        const size_t fi = (((size_t)(w * 4 + kt)) * 64 + l) * 8;
        const bf16x8 bhi = *(const bf16x8*)(path + fi);
        const bf16x8 blo = *(const bf16x8*)(patl + fi);
        aacc = MFMA(alo, bhi, aacc);
        aacc = MFMA(ahi, blo, aacc);
        aacc = MFMA(ahi, bhi, aacc);
    }
    const int col = w * 16 + l15;
    const float ab = loadf(attb, col, flags[R_ATTB]);
    float gated[4];
#pragma unroll
    for (int r = 0; r < 4; ++r) {
        const int rowl = q * 4 + r;
        const float pre = aacc[r] + ab;
        const float s = 1.f / (1.f + expf(-pre));
        const float catv = (float)ixs[0][rowl * IST + col] + (float)ixs[1][rowl * IST + col];
        gated[r] = catv * s;
    }
    __syncthreads();  // all attention reads of ixs done
#pragma unroll
    for (int r = 0; r < 4; ++r) {
        const int rowl = q * 4 + r;
        const bf2 s = split2(gated[r]);
        ixs[0][rowl * IST + col] = s.hi;
        ixs[1][rowl * IST + col] = s.lo;
    }
    __syncthreads();

    mlp_core<false>(ixs[0], ixs[1], h[0], h[1],
                    wpack + OFF_FW1, wpack + OFF_FW1 + SZ_W1,
                    wpack + OFF_FW2, wpack + OFF_FW2 + SZ_W2,
                    wpack + OFF_FWD, wpack + OFF_FWD + SZ_WD,
                    b1, flags[R_FB1], b2, flags[R_FB2], bd, flags[R_FBD],
                    r0, out, nullptr);
}

// ---------------------------------------------------------------------------
extern "C" void kernel_launch(void* const* d_in, const int* in_sizes, int n_in,
                              void* d_out, int out_size, void* d_ws, size_t ws_size,
                              hipStream_t stream)
{
    // ---- resolve input order by size signature (dict order vs sorted) ----
    static const int dictSizes[23] = {8388608, 8388608, 65536, 512, 262144, 512,
                                      32768, 64, 65536, 512, 262144, 512, 32768, 64,
                                      16384, 128, 65536, 512, 262144, 512, 32768, 64, 1};
    static const int dictRole[23]  = {R_X, R_Y, R_SW1, R_SB1, R_SW2, R_SB2, R_SWD, R_SBD,
                                      R_MW1, R_MB1, R_MW2, R_MB2, R_MWD, R_MBD,
                                      R_ATTW, R_ATTB, R_FW1, R_FB1, R_FW2, R_FB2,
                                      R_FWD, R_FBD, -1};
    static const int sortSizes[23] = {128, 16384, 512, 512, 64, 65536, 262144, 32768,
                                      512, 512, 64, 65536, 262144, 32768,
                                      512, 512, 64, 65536, 262144, 32768, 1,
                                      8388608, 8388608};
    static const int sortRole[23]  = {R_ATTB, R_ATTW, R_FB1, R_FB2, R_FBD, R_FW1,
                                      R_FW2, R_FWD, R_MB1, R_MB2, R_MBD, R_MW1,
                                      R_MW2, R_MWD, R_SB1, R_SB2, R_SBD, R_SW1,
                                      R_SW2, R_SWD, -1, R_X, R_Y};
    const void* rp[N_ROLES];
    int rs[N_ROLES];
    for (int i = 0; i < 23 && i < n_in; ++i)
        if (dictRole[i] >= 0) { rp[dictRole[i]] = d_in[i]; rs[dictRole[i]] = in_sizes[i]; }
    {
        bool dictOk = (n_in >= 22);
        for (int i = 0; i < 22 && dictOk; ++i)
            if (in_sizes[i] != dictSizes[i]) dictOk = false;
        if (!dictOk) {
            bool sortOk = (n_in >= 23);
            for (int i = 0; i < 23 && sortOk; ++i)
                if (in_sizes[i] != sortSizes[i]) sortOk = false;
            if (sortOk)
                for (int i = 0; i < 23; ++i)
                    if (sortRole[i] >= 0) { rp[sortRole[i]] = d_in[i]; rs[sortRole[i]] = in_sizes[i]; }
        }
    }

    __bf16* wpack = (__bf16*)d_ws;
    unsigned long long* masks = (unsigned long long*)((char*)d_ws + WS_MASKS);
    int* rrows = (int*)((char*)d_ws + WS_RROWS);
    int* rcnt  = (int*)((char*)d_ws + WS_RCNT);
    int* flags = (int*)((char*)d_ws + WS_FLAGS);

    float* out_f = (float*)d_out;
    float* sub_o = out_f;
    float* mm_o  = out_f + (size_t)BN * 64;
    float* fus_o = out_f + (size_t)2 * BN * 64;

    DetArgs da;
    for (int r = 0; r < N_ROLES; ++r) { da.p[r] = rp[r]; da.n[r] = rs[r]; }
    detect_kernel<<<N_ROLES, 256, 0, stream>>>(da, flags, rcnt);

    PackArgs pa;
    const int prole[10] = {R_SW1, R_SW2, R_SWD, R_MW1, R_MW2, R_MWD,
                           R_FW1, R_FW2, R_FWD, R_ATTW};
    const int Ks[10]   = {128, 512, 512, 128, 512, 512, 128, 512, 512, 128};
    const int Ns[10]   = {512, 512, 64, 512, 512, 64, 512, 512, 64, 128};
    const int offs[10] = {OFF_SW1, OFF_SW2, OFF_SWD, OFF_MW1, OFF_MW2,
                          OFF_MWD, OFF_FW1, OFF_FW2, OFF_FWD, OFF_ATT};
    for (int i = 0; i < 10; ++i) {
        pa.src[i] = rp[prole[i]];
        pa.K[i] = Ks[i];
        pa.N[i] = Ns[i];
        pa.off[i] = offs[i];
        pa.role[i] = prole[i];
    }
    pack_weights<<<dim3(128, 10), 256, 0, stream>>>(pa, wpack, flags);

    sub_mfma<<<BN / 16, 512, 0, stream>>>(
        rp[R_X], wpack, rp[R_SB1], rp[R_SB2], rp[R_SBD], flags,
        sub_o, masks, rrows, rcnt);

    rescue_kernel<<<512, 256, 0, stream>>>(
        rp[R_X], rp[R_SW1], rp[R_SB1], rp[R_SW2], rp[R_SB2], rp[R_SWD], rp[R_SBD],
        flags, rrows, rcnt, sub_o, masks);

    mm_mfma<<<BN / 16, 512, 0, stream>>>(
        masks, rp[R_Y], wpack, rp[R_MB1], rp[R_MB2], rp[R_MBD], flags, mm_o);

    fusion_mfma<<<BN / 16, 512, 0, stream>>>(
        sub_o, mm_o, wpack, rp[R_ATTB], rp[R_FB1], rp[R_FB2], rp[R_FBD],
        flags, fus_o);
}